// Round 8
// baseline (169.722 us; speedup 1.0000x reference)
//
#include <hip/hip_runtime.h>

#define NH 8
#define DH 64
#define SL 1024
#define NB 8
#define DIN 512
#define DOUT 512
#define PS 72  // P-tile LDS row stride in ushorts

typedef __bf16 bf16x8 __attribute__((ext_vector_type(8)));
typedef float floatx4 __attribute__((ext_vector_type(4)));
typedef unsigned short ushortx8 __attribute__((ext_vector_type(8)));

__device__ __forceinline__ unsigned short f2bf(float f) {
    unsigned int u = __builtin_bit_cast(unsigned int, f);
    u += 0x7FFFu + ((u >> 16) & 1u);
    return (unsigned short)(u >> 16);
}

__device__ __forceinline__ floatx4 mfma_bf16(bf16x8 a, bf16x8 b, floatx4 c) {
    return __builtin_amdgcn_mfma_f32_16x16x32_bf16(a, b, c, 0, 0, 0);
}

__device__ __forceinline__ void gld_lds16(const unsigned short* g, unsigned short* l) {
    __builtin_amdgcn_global_load_lds(
        (const __attribute__((address_space(1))) unsigned int*)g,
        (__attribute__((address_space(3))) unsigned int*)l, 16, 0, 0);
}

// bf16-truncate-pack two floats into one u32 (low short = bf(a), high = bf(b))
__device__ __forceinline__ unsigned int pack_bf2(float a, float b) {
    return __builtin_amdgcn_perm(__builtin_bit_cast(unsigned int, b),
                                 __builtin_bit_cast(unsigned int, a), 0x07060302u);
}

// RNE-rounding pack of two f32 -> u32 of 2xbf16 (no builtin on gfx950; T12 recipe)
__device__ __forceinline__ unsigned int cvt_pk_bf16(float lo, float hi) {
    unsigned int r;
    asm("v_cvt_pk_bf16_f32 %0, %1, %2" : "=v"(r) : "v"(lo), "v"(hi));
    return r;
}

// W -> transposed bf16, tiled+swizzled (X conversion now fused into proj_kernel).
__global__ __launch_bounds__(256) void wt_kernel(const float* __restrict__ WQ,
                                                 const float* __restrict__ WK,
                                                 const float* __restrict__ WV,
                                                 unsigned short* __restrict__ wt) {
    __shared__ unsigned short tile[64][68];
    const int bid = blockIdx.x;
    const int z = bid >> 6;
    const int r = bid & 63;
    const float* W = (z == 0) ? WQ : (z == 1 ? WK : WV);
    const int k0 = (r >> 3) * 64, n0 = (r & 7) * 64;
    const int tn = threadIdx.x & 63, tk = threadIdx.x >> 6;
#pragma unroll
    for (int i = 0; i < 16; ++i) {
        const int kk = tk + i * 4;
        tile[tn][kk] = f2bf(W[(k0 + kk) * DOUT + n0 + tn]);
    }
    __syncthreads();
#pragma unroll
    for (int i = 0; i < 16; ++i) {
        const int nn = tk + i * 4;
        const int n = n0 + nn, k = k0 + tn;
        const int dst = (((z * 4 + (n >> 7)) * 8 + (k >> 6)) * 128 + (n & 127)) * 64 +
                        ((((k >> 3) & 7) ^ (n & 7)) * 8) + (k & 7);
        wt[dst] = tile[nn][tn];
    }
}

// m97-style GEMM, 128x128xBK64, 2-phase pipelined (R14), LDS-assembled epilogue.
// R15/R16: A-operand staged DIRECTLY from fp32 X (xb round-trip removed:
// -25 MB write, -25 MB read, -6144 prep blocks). Per K-step each thread loads
// 128 B fp32 (8x dwordx4, issued BEFORE compute so latency hides under MFMAs),
// converts via v_cvt_pk_bf16_f32, ds_write_b128s the same swizzled in-LDS
// image xb had. AWRITE after COMPUTE: in-order vmcnt makes it wait only on the
// A-loads (B's gld_lds16 stay in flight); __syncthreads drains all.
__global__ __launch_bounds__(256) void proj_kernel(const float* __restrict__ Qs,
                                                   const float* __restrict__ Ks,
                                                   const float* __restrict__ Vs,
                                                   const unsigned short* __restrict__ wtt,
                                                   unsigned short* __restrict__ qw,
                                                   unsigned short* __restrict__ ks,
                                                   unsigned short* __restrict__ vs) {
    __shared__ __align__(16) unsigned short S[32768];  // [buf][As 8192 | Bs 8192] x2
    const int z = blockIdx.y;
    const float* X = (z == 0) ? Qs : (z == 1 ? Ks : Vs);
    const int wg = blockIdx.x;        // 0..255
    const int ix = wg >> 3;           // index within this XCD's chunk (round-robin model)
    const int mblk = (wg & 7) * 8 + (ix >> 2);
    const int nblk = ix & 3;
    const int w = threadIdx.x >> 6, lane = threadIdx.x & 63;
    const int tid = threadIdx.x;
    const int l15 = lane & 15, quad = lane >> 4;
    const int wm = w >> 1, wn = w & 1;
    const int soff = lane * 8;  // identity: swizzle lives in the stored wt layout
    const unsigned short* Bb = wtt + (z * 4 + nblk) * 8 * 8192 + (w * 4) * 512 + soff;

    // A-staging geometry: thread t owns tile row t>>1, k-halfchunk (t&1)*32.
    const int arow = tid >> 1;            // 0..127
    const int kc0 = (tid & 1) * 4;        // first 8-wide chunk index (0 or 4)
    const float* Xp = X + (size_t)(mblk * 128 + arow) * 512 + (tid & 1) * 32;

    floatx4 acc[4][4];
#pragma unroll
    for (int i = 0; i < 4; ++i)
#pragma unroll
        for (int j = 0; j < 4; ++j) acc[i][j] = floatx4{0.f, 0.f, 0.f, 0.f};

    float4 aA0, aA1, aA2, aA3, aA4, aA5, aA6, aA7;  // A prefetch (32 VGPR)
    auto ALOAD = [&](int kblk) {
        const float* p = Xp + kblk * 64;
        aA0 = *(const float4*)(p);      aA1 = *(const float4*)(p + 4);
        aA2 = *(const float4*)(p + 8);  aA3 = *(const float4*)(p + 12);
        aA4 = *(const float4*)(p + 16); aA5 = *(const float4*)(p + 20);
        aA6 = *(const float4*)(p + 24); aA7 = *(const float4*)(p + 28);
    };
    auto AWRITE = [&](int buf) {
        unsigned short* base = &S[buf * 16384 + arow * 64];
        const int rx = arow & 7;
#define AW(I, LO, HI)                                                      \
    {                                                                      \
        uint4 wv;                                                          \
        wv.x = cvt_pk_bf16(LO.x, LO.y);                                    \
        wv.y = cvt_pk_bf16(LO.z, LO.w);                                    \
        wv.z = cvt_pk_bf16(HI.x, HI.y);                                    \
        wv.w = cvt_pk_bf16(HI.z, HI.w);                                    \
        *(uint4*)(base + (((kc0 + I) ^ rx) * 8)) = wv;                     \
    }
        AW(0, aA0, aA1) AW(1, aA2, aA3) AW(2, aA4, aA5) AW(3, aA6, aA7)
#undef AW
    };
    auto BSTAGE = [&](int buf, int kblk) {
        unsigned short* Bsw = &S[buf * 16384 + 8192 + (w * 4) * 512];
#pragma unroll
        for (int i = 0; i < 4; ++i)
            gld_lds16(Bb + kblk * 8192 + i * 512, Bsw + i * 512);
    };
    auto COMPUTE = [&](int buf) {
        const unsigned short* Asb = &S[buf * 16384];
        const unsigned short* Bsb = &S[buf * 16384 + 8192];
#pragma unroll
        for (int ksub = 0; ksub < 2; ++ksub) {
            bf16x8 af[4], bfr[4];
#pragma unroll
            for (int mi = 0; mi < 4; ++mi) {
                const int row = wm * 64 + mi * 16 + l15;
                af[mi] = *(const bf16x8*)&Asb[row * 64 + (((quad + ksub * 4) ^ (l15 & 7)) * 8)];
            }
#pragma unroll
            for (int nt = 0; nt < 4; ++nt) {
                const int row = wn * 64 + nt * 16 + l15;
                bfr[nt] = *(const bf16x8*)&Bsb[row * 64 + (((quad + ksub * 4) ^ (l15 & 7)) * 8)];
            }
#pragma unroll
            for (int mi = 0; mi < 4; ++mi)
#pragma unroll
                for (int nt = 0; nt < 4; ++nt)
                    acc[mi][nt] = mfma_bf16(af[mi], bfr[nt], acc[mi][nt]);
        }
    };

    // 2-phase pipeline: stage(k+1) in flight during compute(k).
    ALOAD(0);
    BSTAGE(0, 0);
    AWRITE(0);
    __syncthreads();  // buf0 ready
    for (int kblk = 0; kblk < 7; ++kblk) {
        ALOAD(kblk + 1);                  // A fp32 -> regs (latency under compute)
        BSTAGE((kblk + 1) & 1, kblk + 1); // B gld_lds16 in flight
        COMPUTE(kblk & 1);
        AWRITE((kblk + 1) & 1);           // waits A-loads only; cvt+ds_write
        __syncthreads();                  // drains all: next buf ready
    }
    COMPUTE(1);

    // ---- epilogue: build output-byte-exact image in LDS (aliases buf0) ----
    __syncthreads();
#pragma unroll
    for (int mi = 0; mi < 4; ++mi)
#pragma unroll
        for (int nt = 0; nt < 4; ++nt)
#pragma unroll
            for (int r = 0; r < 4; ++r) {
                const int a = wm * 64 + mi * 16 + quad * 4 + r;   // tile row 0..127
                const int c = wn * 64 + nt * 16 + l15;            // tile col 0..127
                const int h = c >> 6, dh = c & 63;
                float v = acc[mi][nt][r];
                int lidx;
                if (z == 0) {
                    v *= 0.18033688f;  // 0.125 * log2(e): attn uses exp2
                    // q fragment-blocked image: [h][ltile 8][kc 8][l15 16][8]
                    lidx = h * 8192 + (a >> 4) * 1024 + (dh >> 3) * 128 + (a & 15) * 8 + (dh & 7);
                } else if (z == 1) {
                    lidx = (((((h << 3) + (a >> 4)) << 1) | (dh >> 5))) * 512 +
                           (a & 15) * 32 + (dh & 31);
                } else {
                    const int s64 = ((a & 15) << 2) | ((a >> 4) & 3);
                    lidx = ((((h << 1) | (a >> 6)) << 1) | (s64 >> 5)) * 2048 +
                           dh * 32 + (s64 & 31);
                }
                S[lidx] = f2bf(v);
            }
    __syncthreads();

    const int b = mblk >> 3;
    const int li0 = (mblk & 7) * 128;
    unsigned short* outp = (z == 0) ? qw : (z == 1 ? ks : vs);
#pragma unroll
    for (int j = 0; j < 8; ++j) {
        const int off = j * 2048 + tid * 8;
        const ushortx8 val = *(const ushortx8*)(S + off);
        int gidx;
        if (z == 0) {
            const int h = off >> 13, o13 = off & 8191;
            gidx = ((b * 8 + nblk * 2 + h) * 64 + (li0 >> 4) + (o13 >> 10)) * 1024 + (o13 & 1023);
        } else if (z == 1) {
            const int region = off >> 9, pos = off & 511;
            const int h = region >> 4, g = (region >> 1) & 7, d5 = region & 1;
            gidx = (((b * 8 + nblk * 2 + h) * 64 + (li0 >> 4) + g) * 2 + d5) * 512 + pos;
        } else {
            const int region = off >> 11, pos = off & 2047;
            const int h = region >> 2, l6 = (region >> 1) & 1, s5 = region & 1;
            gidx = ((b * 8 + nblk * 2 + h) * 32 + (li0 >> 5) + l6 * 2 + s5) * 2048 + pos;
        }
        *(ushortx8*)(outp + gidx) = val;
    }
}

// One K-frame (64 keys) for a 32-row q-pair. ALL state in individually named
// locals / references. Compile-time DOMASK.
template <bool DOMASK>
__device__ __forceinline__ void frame_step(
    int kt, int m0, int l15, int quad,
    const unsigned short* __restrict__ ksb,
    const unsigned short* __restrict__ vsb,
    unsigned short* myPs,
    bf16x8 aQA0, bf16x8 aQA1, bf16x8 aQB0, bf16x8 aQB1,
    floatx4& oA0, floatx4& oA1, floatx4& oA2, floatx4& oA3,
    floatx4& oB0, floatx4& oB1, floatx4& oB2, floatx4& oB3,
    float& lA0, float& lA1, float& lA2, float& lA3,
    float& lB0, float& lB1, float& lB2, float& lB3) {
    const floatx4 zf = {0.f, 0.f, 0.f, 0.f};
    const unsigned short* kp = ksb + (kt >> 4) * 1024;
    floatx4 sA0 = zf, sA1 = zf, sA2 = zf, sA3 = zf;
    floatx4 sB0 = zf, sB1 = zf, sB2 = zf, sB3 = zf;
    __builtin_amdgcn_s_setprio(1);
#define QK_T(T, SA, SB)                                                     \
    if (!DOMASK || (kt + T * 16 <= m0 + 31)) {                              \
        const bf16x8 k0_ = *(const bf16x8*)(kp + T * 1024);                 \
        const bf16x8 k1_ = *(const bf16x8*)(kp + T * 1024 + 512);           \
        if (!DOMASK || (kt + T * 16 <= m0 + 15))                            \
            SA = mfma_bf16(aQA1, k1_, mfma_bf16(aQA0, k0_, zf));            \
        SB = mfma_bf16(aQB1, k1_, mfma_bf16(aQB0, k0_, zf));                \
    }
    QK_T(0, sA0, sB0)
    QK_T(1, sA1, sB1)
    QK_T(2, sA2, sB2)
    QK_T(3, sA3, sB3)
#undef QK_T
    __builtin_amdgcn_s_setprio(0);
    // V after K: vmcnt in-order, QK must not wait behind V; V hides under TAIL.
    const unsigned short* vb = vsb + (kt >> 5) * 2048;
    const bf16x8 v00 = *(const bf16x8*)(vb);
    const bf16x8 v01 = *(const bf16x8*)(vb + 512);
    const bf16x8 v02 = *(const bf16x8*)(vb + 1024);
    const bf16x8 v03 = *(const bf16x8*)(vb + 1536);
    const bf16x8 v10 = *(const bf16x8*)(vb + 2048);
    const bf16x8 v11 = *(const bf16x8*)(vb + 2560);
    const bf16x8 v12 = *(const bf16x8*)(vb + 3072);
    const bf16x8 v13 = *(const bf16x8*)(vb + 3584);
#define TAIL_R(R, LA, LB)                                                    \
    {                                                                        \
        const int rowA = m0 + quad * 4 + R;                                  \
        float pa0 = __builtin_amdgcn_exp2f(sA0[R]);                          \
        float pa1 = __builtin_amdgcn_exp2f(sA1[R]);                          \
        float pa2 = __builtin_amdgcn_exp2f(sA2[R]);                          \
        float pa3 = __builtin_amdgcn_exp2f(sA3[R]);                          \
        float pb0 = __builtin_amdgcn_exp2f(sB0[R]);                          \
        float pb1 = __builtin_amdgcn_exp2f(sB1[R]);                          \
        float pb2 = __builtin_amdgcn_exp2f(sB2[R]);                          \
        float pb3 = __builtin_amdgcn_exp2f(sB3[R]);                          \
        if (DOMASK) {                                                        \
            if (kt + l15 > rowA) pa0 = 0.f;                                  \
            if (kt + 16 + l15 > rowA) pa1 = 0.f;                             \
            if (kt + 32 + l15 > rowA) pa2 = 0.f;                             \
            if (kt + 48 + l15 > rowA) pa3 = 0.f;                             \
            if (kt + l15 > rowA + 16) pb0 = 0.f;                             \
            if (kt + 16 + l15 > rowA + 16) pb1 = 0.f;                        \
            if (kt + 32 + l15 > rowA + 16) pb2 = 0.f;                        \
            if (kt + 48 + l15 > rowA + 16) pb3 = 0.f;                        \
        }                                                                    \
        LA += (pa0 + pa1) + (pa2 + pa3);                                     \
        LB += (pb0 + pb1) + (pb2 + pb3);                                     \
        uint2 pkA, pkB;                                                      \
        pkA.x = pack_bf2(pa0, pa1);                                          \
        pkA.y = pack_bf2(pa2, pa3);                                          \
        pkB.x = pack_bf2(pb0, pb1);                                          \
        pkB.y = pack_bf2(pb2, pb3);                                          \
        *(uint2*)(myPs + (quad * 4 + R) * PS + l15 * 4) = pkA;               \
        *(uint2*)(myPs + (16 + quad * 4 + R) * PS + l15 * 4) = pkB;          \
    }
    TAIL_R(0, lA0, lB0)
    TAIL_R(1, lA1, lB1)
    TAIL_R(2, lA2, lB2)
    TAIL_R(3, lA3, lB3)
#undef TAIL_R
    __builtin_amdgcn_wave_barrier();
    const bf16x8 aPA0 = *(const bf16x8*)(myPs + l15 * PS + quad * 8);
    const bf16x8 aPA1 = *(const bf16x8*)(myPs + l15 * PS + 32 + quad * 8);
    const bf16x8 aPB0 = *(const bf16x8*)(myPs + (16 + l15) * PS + quad * 8);
    const bf16x8 aPB1 = *(const bf16x8*)(myPs + (16 + l15) * PS + 32 + quad * 8);
    __builtin_amdgcn_wave_barrier();
    __builtin_amdgcn_s_setprio(1);
    oA0 = mfma_bf16(aPA1, v10, mfma_bf16(aPA0, v00, oA0));
    oA1 = mfma_bf16(aPA1, v11, mfma_bf16(aPA0, v01, oA1));
    oA2 = mfma_bf16(aPA1, v12, mfma_bf16(aPA0, v02, oA2));
    oA3 = mfma_bf16(aPA1, v13, mfma_bf16(aPA0, v03, oA3));
    oB0 = mfma_bf16(aPB1, v10, mfma_bf16(aPB0, v00, oB0));
    oB1 = mfma_bf16(aPB1, v11, mfma_bf16(aPB0, v01, oB1));
    oB2 = mfma_bf16(aPB1, v12, mfma_bf16(aPB0, v02, oB2));
    oB3 = mfma_bf16(aPB1, v13, mfma_bf16(aPB0, v03, oB3));
    __builtin_amdgcn_s_setprio(0);
}

// Causal flash attention, split-K, M=32 per wave, named-register state.
__global__ __launch_bounds__(256) void attn_kernel(const unsigned short* __restrict__ qw,
                                                   const unsigned short* __restrict__ ksp,
                                                   const unsigned short* __restrict__ vsp,
                                                   float* __restrict__ out) {
    __shared__ union {
        unsigned short Ps[4][32 * PS];
        float Cb[2][64][42];
    } sh;
    const int w = threadIdx.x >> 6;
    const int lane = threadIdx.x & 63;
    const int l15 = lane & 15, quad = lane >> 4;
    // XCD-locality decode: dispatch slot s -> XCD s&7 (round-robin model).
    const int s_ = blockIdx.x;
    const int xcd = s_ & 7;
    const int idx = s_ >> 3;                 // 0..127
    const int bh = xcd * 8 + (idx & 7);      // XCD i serves heads 8i..8i+7
    const int xb16 = idx >> 3;               // 0..15
    const int b = bh >> 3, h = bh & 7;
    const int p = (w < 2) ? xb16 : 31 - xb16;  // tile-pair index 0..31
    const int half = w & 1;
    const int m0 = p * 32;                   // first q-row of the pair

    // Q fragments for both sub-tiles (2p = A, 2p+1 = B)
    const unsigned short* qpA = qw + (bh * 64 + 2 * p) * 1024 + quad * 128 + l15 * 8;
    const bf16x8 aQA0 = *(const bf16x8*)qpA;
    const bf16x8 aQA1 = *(const bf16x8*)(qpA + 512);
    const bf16x8 aQB0 = *(const bf16x8*)(qpA + 1024);
    const bf16x8 aQB1 = *(const bf16x8*)(qpA + 1536);

    const unsigned short* ksb = ksp + (bh * 64) * 2 * 512 + l15 * 32 + quad * 8;
    const unsigned short* vsb = vsp + (bh * 32 * 64 + l15) * 32 + quad * 8;
    unsigned short* myPs = sh.Ps[w];

    const floatx4 zf = {0.f, 0.f, 0.f, 0.f};
    floatx4 oA0 = zf, oA1 = zf, oA2 = zf, oA3 = zf;
    floatx4 oB0 = zf, oB1 = zf, oB2 = zf, oB3 = zf;
    float lA0 = 0.f, lA1 = 0.f, lA2 = 0.f, lA3 = 0.f;
    float lB0 = 0.f, lB1 = 0.f, lB2 = 0.f, lB3 = 0.f;

    // frames covering keys 0 .. m0+31 (B sub-tile's diagonal)
    const int nf = (m0 + 95) >> 6;
    const int last = nf - 1;
    for (int j = half; j < last; j += 2)
        frame_step<false>(j * 64, m0, l15, quad, ksb, vsb, myPs,
                          aQA0, aQA1, aQB0, aQB1,
                          oA0, oA1, oA2, oA3, oB0, oB1, oB2, oB3,
                          lA0, lA1, lA2, lA3, lB0, lB1, lB2, lB3);
    if ((last & 1) == half)
        frame_step<true>(last * 64, m0, l15, quad, ksb, vsb, myPs,
                         aQA0, aQA1, aQB0, aQB1,
                         oA0, oA1, oA2, oA3, oB0, oB1, oB2, oB3,
                         lA0, lA1, lA2, lA3, lB0, lB1, lB2, lB3);

    // combine split-K partners via LDS (pure addition; union with Ps -> barrier first)
    __syncthreads();
    if (half == 1) {
        float* cb = &sh.Cb[w >> 1][lane][0];
        cb[0] = oA0[0];  cb[1] = oA0[1];  cb[2] = oA0[2];  cb[3] = oA0[3];
        cb[4] = oA1[0];  cb[5] = oA1[1];  cb[6] = oA1[2];  cb[7] = oA1[3];
        cb[8] = oA2[0];  cb[9] = oA2[1];  cb[10] = oA2[2]; cb[11] = oA2[3];
        cb[12] = oA3[0]; cb[13] = oA3[1]; cb[14] = oA3[2]; cb[15] = oA3[3];
        cb[16] = oB0[0]; cb[17] = oB0[1]; cb[18] = oB0[2]; cb[19] = oB0[3];
        cb[20] = oB1[0]; cb[21] = oB1[1]; cb[22] = oB1[2]; cb[23] = oB1[3];
        cb[24] = oB2[0]; cb[25] = oB2[1]; cb[26] = oB2[2]; cb[27] = oB2[3];
        cb[28] = oB3[0]; cb[29] = oB3[1]; cb[30] = oB3[2]; cb[31] = oB3[3];
        cb[32] = lA0; cb[33] = lA1; cb[34] = lA2; cb[35] = lA3;
        cb[36] = lB0; cb[37] = lB1; cb[38] = lB2; cb[39] = lB3;
    }
    __syncthreads();
    if (half == 0) {
        const float* cb = &sh.Cb[w >> 1][lane][0];
        oA0[0] += cb[0];  oA0[1] += cb[1];  oA0[2] += cb[2];  oA0[3] += cb[3];
        oA1[0] += cb[4];  oA1[1] += cb[5];  oA1[2] += cb[6];  oA1[3] += cb[7];
        oA2[0] += cb[8];  oA2[1] += cb[9];  oA2[2] += cb[10]; oA2[3] += cb[11];
        oA3[0] += cb[12]; oA3[1] += cb[13]; oA3[2] += cb[14]; oA3[3] += cb[15];
        oB0[0] += cb[16]; oB0[1] += cb[17]; oB0[2] += cb[18]; oB0[3] += cb[19];
        oB1[0] += cb[20]; oB1[1] += cb[21]; oB1[2] += cb[22]; oB1[3] += cb[23];
        oB2[0] += cb[24]; oB2[1] += cb[25]; oB2[2] += cb[26]; oB2[3] += cb[27];
        oB3[0] += cb[28]; oB3[1] += cb[29]; oB3[2] += cb[30]; oB3[3] += cb[31];
        lA0 += cb[32]; lA1 += cb[33]; lA2 += cb[34]; lA3 += cb[35];
        lB0 += cb[36]; lB1 += cb[37]; lB2 += cb[38]; lB3 += cb[39];
#define OUT_R(R, LA, LB)                                                      \
    {                                                                         \
        float lAr = LA, lBr = LB;                                             \
        lAr += __shfl_xor(lAr, 1); lBr += __shfl_xor(lBr, 1);                 \
        lAr += __shfl_xor(lAr, 2); lBr += __shfl_xor(lBr, 2);                 \
        lAr += __shfl_xor(lAr, 4); lBr += __shfl_xor(lBr, 4);                 \
        lAr += __shfl_xor(lAr, 8); lBr += __shfl_xor(lBr, 8);                 \
        const float invA = 1.0f / lAr;                                        \
        const float invB = 1.0f / lBr;                                        \
        const int rowA = m0 + quad * 4 + R;                                   \
        float* opA = out + (b * SL + rowA) * DOUT + h * DH + l15;             \
        float* opB = opA + 16 * DOUT;                                         \
        opA[0] = oA0[R] * invA;  opA[16] = oA1[R] * invA;                     \
        opA[32] = oA2[R] * invA; opA[48] = oA3[R] * invA;                     \
        opB[0] = oB0[R] * invB;  opB[16] = oB1[R] * invB;                     \
        opB[32] = oB2[R] * invB; opB[48] = oB3[R] * invB;                     \
    }
        OUT_R(0, lA0, lB0)
        OUT_R(1, lA1, lB1)
        OUT_R(2, lA2, lB2)
        OUT_R(3, lA3, lB3)
#undef OUT_R
    }
}

extern "C" void kernel_launch(void* const* d_in, const int* in_sizes, int n_in,
                              void* d_out, int out_size, void* d_ws, size_t ws_size,
                              hipStream_t stream) {
    const float* Qs = (const float*)d_in[0];
    const float* Ks = (const float*)d_in[1];
    const float* Vs = (const float*)d_in[2];
    const float* WQ = (const float*)d_in[3];
    const float* WK = (const float*)d_in[4];
    const float* WV = (const float*)d_in[5];
    float* out = (float*)d_out;

    unsigned short* wt = (unsigned short*)d_ws;          // 3*512*512 (tiled+swz)
    unsigned short* qw = wt + 3 * DIN * DOUT;            // frag-blocked, pre-scaled
    unsigned short* ks = qw + NB * NH * SL * DH;         // blocked
    unsigned short* vs = ks + NB * NH * SL * DH;         // blocked+permuted

    wt_kernel<<<dim3(192), 256, 0, stream>>>(WQ, WK, WV, wt);
    proj_kernel<<<dim3(256, 3), 256, 0, stream>>>(Qs, Ks, Vs, wt, qw, ks, vs);
    attn_kernel<<<dim3(1024), 256, 0, stream>>>(qw, ks, vs, out);
}

// Round 9
// 156.353 us; speedup vs baseline: 1.0855x; 1.0855x over previous
//
#include <hip/hip_runtime.h>

#define NH 8
#define DH 64
#define SL 1024
#define NB 8
#define DIN 512
#define DOUT 512
#define PS 72  // P-tile LDS row stride in ushorts

typedef __bf16 bf16x8 __attribute__((ext_vector_type(8)));
typedef float floatx4 __attribute__((ext_vector_type(4)));
typedef unsigned short ushortx8 __attribute__((ext_vector_type(8)));

__device__ __forceinline__ unsigned short f2bf(float f) {
    unsigned int u = __builtin_bit_cast(unsigned int, f);
    u += 0x7FFFu + ((u >> 16) & 1u);
    return (unsigned short)(u >> 16);
}

__device__ __forceinline__ floatx4 mfma_bf16(bf16x8 a, bf16x8 b, floatx4 c) {
    return __builtin_amdgcn_mfma_f32_16x16x32_bf16(a, b, c, 0, 0, 0);
}

__device__ __forceinline__ void gld_lds16(const unsigned short* g, unsigned short* l) {
    __builtin_amdgcn_global_load_lds(
        (const __attribute__((address_space(1))) unsigned int*)g,
        (__attribute__((address_space(3))) unsigned int*)l, 16, 0, 0);
}

// bf16-truncate-pack two floats into one u32 (low short = bf(a), high = bf(b))
__device__ __forceinline__ unsigned int pack_bf2(float a, float b) {
    return __builtin_amdgcn_perm(__builtin_bit_cast(unsigned int, b),
                                 __builtin_bit_cast(unsigned int, a), 0x07060302u);
}

// Merged prep kernel:
//  blocks [0, 6144): X fp32 -> bf16 tiled+swizzled
//  blocks [6144, 6336): W -> transposed bf16 tiled+swizzled
// (R16's X->proj fusion REVERTED: reg-staged A (global->reg->cvt->ds_write)
// put cvt+ds_write on the critical path and doubled staged bytes; proj went
// 40->64 us. m151: direct global_load_lds beats reg-staging when linear LDS
// image works. The xb round-trip is the cheaper form.)
__global__ __launch_bounds__(256) void prep_kernel(const float* __restrict__ Qs,
                                                   const float* __restrict__ Ks,
                                                   const float* __restrict__ Vs,
                                                   const float* __restrict__ WQ,
                                                   const float* __restrict__ WK,
                                                   const float* __restrict__ WV,
                                                   unsigned short* __restrict__ xb,
                                                   unsigned short* __restrict__ wt) {
    __shared__ unsigned short tile[64][68];
    const int bid = blockIdx.x;
    if (bid < 6144) {
        // ---- X conversion: xb[z][(row/128)*8 + k/64][row%128][((k%64/8)^(row&7))*8 + k%8]
        const int z = bid >> 11;
        const float* X = (z == 0) ? Qs : (z == 1 ? Ks : Vs);
        const int t = (bid & 2047) * 256 + threadIdx.x;
        const int row = t >> 6, c = t & 63;
        const float4 a = *(const float4*)(X + t * 8);
        const float4 b = *(const float4*)(X + t * 8 + 4);
        ushortx8 o;
        o[0] = f2bf(a.x); o[1] = f2bf(a.y); o[2] = f2bf(a.z); o[3] = f2bf(a.w);
        o[4] = f2bf(b.x); o[5] = f2bf(b.y); o[6] = f2bf(b.z); o[7] = f2bf(b.w);
        const int dst = (((row >> 7) * 8 + (c >> 3)) * 128 + (row & 127)) * 64 +
                        (((c & 7) ^ (row & 7)) * 8);
        *(ushortx8*)(xb + z * 8192 * DIN + dst) = o;
    } else {
        // ---- W transpose: wt[(z*4+n/128)*8 + k/64][n%128][swz chunk]
        const int b2 = bid - 6144;
        const int z = b2 >> 6;
        const int r = b2 & 63;
        const float* W = (z == 0) ? WQ : (z == 1 ? WK : WV);
        const int k0 = (r >> 3) * 64, n0 = (r & 7) * 64;
        const int tn = threadIdx.x & 63, tk = threadIdx.x >> 6;
#pragma unroll
        for (int i = 0; i < 16; ++i) {
            const int kk = tk + i * 4;
            tile[tn][kk] = f2bf(W[(k0 + kk) * DOUT + n0 + tn]);
        }
        __syncthreads();
#pragma unroll
        for (int i = 0; i < 16; ++i) {
            const int nn = tk + i * 4;
            const int n = n0 + nn, k = k0 + tn;
            const int dst = (((z * 4 + (n >> 7)) * 8 + (k >> 6)) * 128 + (n & 127)) * 64 +
                            ((((k >> 3) & 7) ^ (n & 7)) * 8) + (k & 7);
            wt[dst] = tile[nn][tn];
        }
    }
}

// m97-style GEMM, 128x128xBK64, global_load_lds staging, LDS-assembled epilogue.
// R14 T3 2-phase pipeline (best measured): stage(k+1) in flight during
// compute(k); one barrier per K-step. Epilogue image aliases buf0.
__global__ __launch_bounds__(256) void proj_kernel(const unsigned short* __restrict__ xbt,
                                                   const unsigned short* __restrict__ wtt,
                                                   unsigned short* __restrict__ qw,
                                                   unsigned short* __restrict__ ks,
                                                   unsigned short* __restrict__ vs) {
    __shared__ __align__(16) unsigned short S[32768];  // [buf][As 8192 | Bs 8192] x2
    const int z = blockIdx.y;
    const int wg = blockIdx.x;        // 0..255
    const int ix = wg >> 3;           // index within this XCD's chunk (round-robin model)
    const int mblk = (wg & 7) * 8 + (ix >> 2);
    const int nblk = ix & 3;
    const int w = threadIdx.x >> 6, lane = threadIdx.x & 63;
    const int l15 = lane & 15, quad = lane >> 4;
    const int wm = w >> 1, wn = w & 1;
    const int soff = lane * 8;  // identity: swizzle lives in the stored layout
    const unsigned short* Ab = xbt + z * (8192 * DIN) + mblk * 8 * 8192 + (w * 4) * 512 + soff;
    const unsigned short* Bb = wtt + (z * 4 + nblk) * 8 * 8192 + (w * 4) * 512 + soff;

    floatx4 acc[4][4];
#pragma unroll
    for (int i = 0; i < 4; ++i)
#pragma unroll
        for (int j = 0; j < 4; ++j) acc[i][j] = floatx4{0.f, 0.f, 0.f, 0.f};

    auto STAGE = [&](int buf, int kblk) {
        unsigned short* Asw = &S[buf * 16384 + (w * 4) * 512];
        unsigned short* Bsw = &S[buf * 16384 + 8192 + (w * 4) * 512];
#pragma unroll
        for (int i = 0; i < 4; ++i) {
            gld_lds16(Ab + kblk * 8192 + i * 512, Asw + i * 512);
            gld_lds16(Bb + kblk * 8192 + i * 512, Bsw + i * 512);
        }
    };

    auto COMPUTE = [&](int buf) {
        const unsigned short* Asb = &S[buf * 16384];
        const unsigned short* Bsb = &S[buf * 16384 + 8192];
#pragma unroll
        for (int ksub = 0; ksub < 2; ++ksub) {
            bf16x8 af[4], bfr[4];
#pragma unroll
            for (int mi = 0; mi < 4; ++mi) {
                const int row = wm * 64 + mi * 16 + l15;
                af[mi] = *(const bf16x8*)&Asb[row * 64 + (((quad + ksub * 4) ^ (l15 & 7)) * 8)];
            }
#pragma unroll
            for (int nt = 0; nt < 4; ++nt) {
                const int row = wn * 64 + nt * 16 + l15;
                bfr[nt] = *(const bf16x8*)&Bsb[row * 64 + (((quad + ksub * 4) ^ (l15 & 7)) * 8)];
            }
#pragma unroll
            for (int mi = 0; mi < 4; ++mi)
#pragma unroll
                for (int nt = 0; nt < 4; ++nt)
                    acc[mi][nt] = mfma_bf16(af[mi], bfr[nt], acc[mi][nt]);
        }
    };

    // T3 2-phase: prologue stage + drain, then overlap stage(k+1) with compute(k).
    STAGE(0, 0);
    __syncthreads();  // vmcnt(0) drain: buf0 ready
    for (int kblk = 0; kblk < 7; ++kblk) {
        STAGE((kblk + 1) & 1, kblk + 1);  // in flight during compute below
        COMPUTE(kblk & 1);
        __syncthreads();  // drains vmcnt(0): next buf ready; all waves done with cur
    }
    COMPUTE(1);

    // ---- epilogue: build output-byte-exact image in LDS (aliases buf0) ----
    __syncthreads();
#pragma unroll
    for (int mi = 0; mi < 4; ++mi)
#pragma unroll
        for (int nt = 0; nt < 4; ++nt)
#pragma unroll
            for (int r = 0; r < 4; ++r) {
                const int a = wm * 64 + mi * 16 + quad * 4 + r;   // tile row 0..127
                const int c = wn * 64 + nt * 16 + l15;            // tile col 0..127
                const int h = c >> 6, dh = c & 63;
                float v = acc[mi][nt][r];
                int lidx;
                if (z == 0) {
                    v *= 0.18033688f;  // 0.125 * log2(e): attn uses exp2
                    // q fragment-blocked image: [h][ltile 8][kc 8][l15 16][8]
                    lidx = h * 8192 + (a >> 4) * 1024 + (dh >> 3) * 128 + (a & 15) * 8 + (dh & 7);
                } else if (z == 1) {
                    lidx = (((((h << 3) + (a >> 4)) << 1) | (dh >> 5))) * 512 +
                           (a & 15) * 32 + (dh & 31);
                } else {
                    const int s64 = ((a & 15) << 2) | ((a >> 4) & 3);
                    lidx = ((((h << 1) | (a >> 6)) << 1) | (s64 >> 5)) * 2048 +
                           dh * 32 + (s64 & 31);
                }
                S[lidx] = f2bf(v);
            }
    __syncthreads();

    const int b = mblk >> 3;
    const int li0 = (mblk & 7) * 128;
    const int tid = threadIdx.x;
    unsigned short* outp = (z == 0) ? qw : (z == 1 ? ks : vs);
#pragma unroll
    for (int j = 0; j < 8; ++j) {
        const int off = j * 2048 + tid * 8;
        const ushortx8 val = *(const ushortx8*)(S + off);
        int gidx;
        if (z == 0) {
            const int h = off >> 13, o13 = off & 8191;
            gidx = ((b * 8 + nblk * 2 + h) * 64 + (li0 >> 4) + (o13 >> 10)) * 1024 + (o13 & 1023);
        } else if (z == 1) {
            const int region = off >> 9, pos = off & 511;
            const int h = region >> 4, g = (region >> 1) & 7, d5 = region & 1;
            gidx = (((b * 8 + nblk * 2 + h) * 64 + (li0 >> 4) + g) * 2 + d5) * 512 + pos;
        } else {
            const int region = off >> 11, pos = off & 2047;
            const int h = region >> 2, l6 = (region >> 1) & 1, s5 = region & 1;
            gidx = ((b * 8 + nblk * 2 + h) * 32 + (li0 >> 5) + l6 * 2 + s5) * 2048 + pos;
        }
        *(ushortx8*)(outp + gidx) = val;
    }
}

// One K-frame (64 keys) for a 32-row q-pair. ALL state in individually named
// locals / references. Compile-time DOMASK.
template <bool DOMASK>
__device__ __forceinline__ void frame_step(
    int kt, int m0, int l15, int quad,
    const unsigned short* __restrict__ ksb,
    const unsigned short* __restrict__ vsb,
    unsigned short* myPs,
    bf16x8 aQA0, bf16x8 aQA1, bf16x8 aQB0, bf16x8 aQB1,
    floatx4& oA0, floatx4& oA1, floatx4& oA2, floatx4& oA3,
    floatx4& oB0, floatx4& oB1, floatx4& oB2, floatx4& oB3,
    float& lA0, float& lA1, float& lA2, float& lA3,
    float& lB0, float& lB1, float& lB2, float& lB3) {
    const floatx4 zf = {0.f, 0.f, 0.f, 0.f};
    const unsigned short* kp = ksb + (kt >> 4) * 1024;
    floatx4 sA0 = zf, sA1 = zf, sA2 = zf, sA3 = zf;
    floatx4 sB0 = zf, sB1 = zf, sB2 = zf, sB3 = zf;
    __builtin_amdgcn_s_setprio(1);
#define QK_T(T, SA, SB)                                                     \
    if (!DOMASK || (kt + T * 16 <= m0 + 31)) {                              \
        const bf16x8 k0_ = *(const bf16x8*)(kp + T * 1024);                 \
        const bf16x8 k1_ = *(const bf16x8*)(kp + T * 1024 + 512);           \
        if (!DOMASK || (kt + T * 16 <= m0 + 15))                            \
            SA = mfma_bf16(aQA1, k1_, mfma_bf16(aQA0, k0_, zf));            \
        SB = mfma_bf16(aQB1, k1_, mfma_bf16(aQB0, k0_, zf));                \
    }
    QK_T(0, sA0, sB0)
    QK_T(1, sA1, sB1)
    QK_T(2, sA2, sB2)
    QK_T(3, sA3, sB3)
#undef QK_T
    __builtin_amdgcn_s_setprio(0);
    // V after K: vmcnt in-order, QK must not wait behind V; V hides under TAIL.
    const unsigned short* vb = vsb + (kt >> 5) * 2048;
    const bf16x8 v00 = *(const bf16x8*)(vb);
    const bf16x8 v01 = *(const bf16x8*)(vb + 512);
    const bf16x8 v02 = *(const bf16x8*)(vb + 1024);
    const bf16x8 v03 = *(const bf16x8*)(vb + 1536);
    const bf16x8 v10 = *(const bf16x8*)(vb + 2048);
    const bf16x8 v11 = *(const bf16x8*)(vb + 2560);
    const bf16x8 v12 = *(const bf16x8*)(vb + 3072);
    const bf16x8 v13 = *(const bf16x8*)(vb + 3584);
#define TAIL_R(R, LA, LB)                                                    \
    {                                                                        \
        const int rowA = m0 + quad * 4 + R;                                  \
        float pa0 = __builtin_amdgcn_exp2f(sA0[R]);                          \
        float pa1 = __builtin_amdgcn_exp2f(sA1[R]);                          \
        float pa2 = __builtin_amdgcn_exp2f(sA2[R]);                          \
        float pa3 = __builtin_amdgcn_exp2f(sA3[R]);                          \
        float pb0 = __builtin_amdgcn_exp2f(sB0[R]);                          \
        float pb1 = __builtin_amdgcn_exp2f(sB1[R]);                          \
        float pb2 = __builtin_amdgcn_exp2f(sB2[R]);                          \
        float pb3 = __builtin_amdgcn_exp2f(sB3[R]);                          \
        if (DOMASK) {                                                        \
            if (kt + l15 > rowA) pa0 = 0.f;                                  \
            if (kt + 16 + l15 > rowA) pa1 = 0.f;                             \
            if (kt + 32 + l15 > rowA) pa2 = 0.f;                             \
            if (kt + 48 + l15 > rowA) pa3 = 0.f;                             \
            if (kt + l15 > rowA + 16) pb0 = 0.f;                             \
            if (kt + 16 + l15 > rowA + 16) pb1 = 0.f;                        \
            if (kt + 32 + l15 > rowA + 16) pb2 = 0.f;                        \
            if (kt + 48 + l15 > rowA + 16) pb3 = 0.f;                        \
        }                                                                    \
        LA += (pa0 + pa1) + (pa2 + pa3);                                     \
        LB += (pb0 + pb1) + (pb2 + pb3);                                     \
        uint2 pkA, pkB;                                                      \
        pkA.x = pack_bf2(pa0, pa1);                                          \
        pkA.y = pack_bf2(pa2, pa3);                                          \
        pkB.x = pack_bf2(pb0, pb1);                                          \
        pkB.y = pack_bf2(pb2, pb3);                                          \
        *(uint2*)(myPs + (quad * 4 + R) * PS + l15 * 4) = pkA;               \
        *(uint2*)(myPs + (16 + quad * 4 + R) * PS + l15 * 4) = pkB;          \
    }
    TAIL_R(0, lA0, lB0)
    TAIL_R(1, lA1, lB1)
    TAIL_R(2, lA2, lB2)
    TAIL_R(3, lA3, lB3)
#undef TAIL_R
    __builtin_amdgcn_wave_barrier();
    const bf16x8 aPA0 = *(const bf16x8*)(myPs + l15 * PS + quad * 8);
    const bf16x8 aPA1 = *(const bf16x8*)(myPs + l15 * PS + 32 + quad * 8);
    const bf16x8 aPB0 = *(const bf16x8*)(myPs + (16 + l15) * PS + quad * 8);
    const bf16x8 aPB1 = *(const bf16x8*)(myPs + (16 + l15) * PS + 32 + quad * 8);
    __builtin_amdgcn_wave_barrier();
    __builtin_amdgcn_s_setprio(1);
    oA0 = mfma_bf16(aPA1, v10, mfma_bf16(aPA0, v00, oA0));
    oA1 = mfma_bf16(aPA1, v11, mfma_bf16(aPA0, v01, oA1));
    oA2 = mfma_bf16(aPA1, v12, mfma_bf16(aPA0, v02, oA2));
    oA3 = mfma_bf16(aPA1, v13, mfma_bf16(aPA0, v03, oA3));
    oB0 = mfma_bf16(aPB1, v10, mfma_bf16(aPB0, v00, oB0));
    oB1 = mfma_bf16(aPB1, v11, mfma_bf16(aPB0, v01, oB1));
    oB2 = mfma_bf16(aPB1, v12, mfma_bf16(aPB0, v02, oB2));
    oB3 = mfma_bf16(aPB1, v13, mfma_bf16(aPB0, v03, oB3));
    __builtin_amdgcn_s_setprio(0);
}

// Causal flash attention, split-K, M=32 per wave, named-register state.
__global__ __launch_bounds__(256) void attn_kernel(const unsigned short* __restrict__ qw,
                                                   const unsigned short* __restrict__ ksp,
                                                   const unsigned short* __restrict__ vsp,
                                                   float* __restrict__ out) {
    __shared__ union {
        unsigned short Ps[4][32 * PS];
        float Cb[2][64][42];
    } sh;
    const int w = threadIdx.x >> 6;
    const int lane = threadIdx.x & 63;
    const int l15 = lane & 15, quad = lane >> 4;
    // XCD-locality decode: dispatch slot s -> XCD s&7 (round-robin model).
    const int s_ = blockIdx.x;
    const int xcd = s_ & 7;
    const int idx = s_ >> 3;                 // 0..127
    const int bh = xcd * 8 + (idx & 7);      // XCD i serves heads 8i..8i+7
    const int xb16 = idx >> 3;               // 0..15
    const int b = bh >> 3, h = bh & 7;
    const int p = (w < 2) ? xb16 : 31 - xb16;  // tile-pair index 0..31
    const int half = w & 1;
    const int m0 = p * 32;                   // first q-row of the pair

    // Q fragments for both sub-tiles (2p = A, 2p+1 = B)
    const unsigned short* qpA = qw + (bh * 64 + 2 * p) * 1024 + quad * 128 + l15 * 8;
    const bf16x8 aQA0 = *(const bf16x8*)qpA;
    const bf16x8 aQA1 = *(const bf16x8*)(qpA + 512);
    const bf16x8 aQB0 = *(const bf16x8*)(qpA + 1024);
    const bf16x8 aQB1 = *(const bf16x8*)(qpA + 1536);

    const unsigned short* ksb = ksp + (bh * 64) * 2 * 512 + l15 * 32 + quad * 8;
    const unsigned short* vsb = vsp + (bh * 32 * 64 + l15) * 32 + quad * 8;
    unsigned short* myPs = sh.Ps[w];

    const floatx4 zf = {0.f, 0.f, 0.f, 0.f};
    floatx4 oA0 = zf, oA1 = zf, oA2 = zf, oA3 = zf;
    floatx4 oB0 = zf, oB1 = zf, oB2 = zf, oB3 = zf;
    float lA0 = 0.f, lA1 = 0.f, lA2 = 0.f, lA3 = 0.f;
    float lB0 = 0.f, lB1 = 0.f, lB2 = 0.f, lB3 = 0.f;

    // frames covering keys 0 .. m0+31 (B sub-tile's diagonal)
    const int nf = (m0 + 95) >> 6;
    const int last = nf - 1;
    for (int j = half; j < last; j += 2)
        frame_step<false>(j * 64, m0, l15, quad, ksb, vsb, myPs,
                          aQA0, aQA1, aQB0, aQB1,
                          oA0, oA1, oA2, oA3, oB0, oB1, oB2, oB3,
                          lA0, lA1, lA2, lA3, lB0, lB1, lB2, lB3);
    if ((last & 1) == half)
        frame_step<true>(last * 64, m0, l15, quad, ksb, vsb, myPs,
                         aQA0, aQA1, aQB0, aQB1,
                         oA0, oA1, oA2, oA3, oB0, oB1, oB2, oB3,
                         lA0, lA1, lA2, lA3, lB0, lB1, lB2, lB3);

    // combine split-K partners via LDS (pure addition; union with Ps -> barrier first)
    __syncthreads();
    if (half == 1) {
        float* cb = &sh.Cb[w >> 1][lane][0];
        cb[0] = oA0[0];  cb[1] = oA0[1];  cb[2] = oA0[2];  cb[3] = oA0[3];
        cb[4] = oA1[0];  cb[5] = oA1[1];  cb[6] = oA1[2];  cb[7] = oA1[3];
        cb[8] = oA2[0];  cb[9] = oA2[1];  cb[10] = oA2[2]; cb[11] = oA2[3];
        cb[12] = oA3[0]; cb[13] = oA3[1]; cb[14] = oA3[2]; cb[15] = oA3[3];
        cb[16] = oB0[0]; cb[17] = oB0[1]; cb[18] = oB0[2]; cb[19] = oB0[3];
        cb[20] = oB1[0]; cb[21] = oB1[1]; cb[22] = oB1[2]; cb[23] = oB1[3];
        cb[24] = oB2[0]; cb[25] = oB2[1]; cb[26] = oB2[2]; cb[27] = oB2[3];
        cb[28] = oB3[0]; cb[29] = oB3[1]; cb[30] = oB3[2]; cb[31] = oB3[3];
        cb[32] = lA0; cb[33] = lA1; cb[34] = lA2; cb[35] = lA3;
        cb[36] = lB0; cb[37] = lB1; cb[38] = lB2; cb[39] = lB3;
    }
    __syncthreads();
    if (half == 0) {
        const float* cb = &sh.Cb[w >> 1][lane][0];
        oA0[0] += cb[0];  oA0[1] += cb[1];  oA0[2] += cb[2];  oA0[3] += cb[3];
        oA1[0] += cb[4];  oA1[1] += cb[5];  oA1[2] += cb[6];  oA1[3] += cb[7];
        oA2[0] += cb[8];  oA2[1] += cb[9];  oA2[2] += cb[10]; oA2[3] += cb[11];
        oA3[0] += cb[12]; oA3[1] += cb[13]; oA3[2] += cb[14]; oA3[3] += cb[15];
        oB0[0] += cb[16]; oB0[1] += cb[17]; oB0[2] += cb[18]; oB0[3] += cb[19];
        oB1[0] += cb[20]; oB1[1] += cb[21]; oB1[2] += cb[22]; oB1[3] += cb[23];
        oB2[0] += cb[24]; oB2[1] += cb[25]; oB2[2] += cb[26]; oB2[3] += cb[27];
        oB3[0] += cb[28]; oB3[1] += cb[29]; oB3[2] += cb[30]; oB3[3] += cb[31];
        lA0 += cb[32]; lA1 += cb[33]; lA2 += cb[34]; lA3 += cb[35];
        lB0 += cb[36]; lB1 += cb[37]; lB2 += cb[38]; lB3 += cb[39];
#define OUT_R(R, LA, LB)                                                      \
    {                                                                         \
        float lAr = LA, lBr = LB;                                             \
        lAr += __shfl_xor(lAr, 1); lBr += __shfl_xor(lBr, 1);                 \
        lAr += __shfl_xor(lAr, 2); lBr += __shfl_xor(lBr, 2);                 \
        lAr += __shfl_xor(lAr, 4); lBr += __shfl_xor(lBr, 4);                 \
        lAr += __shfl_xor(lAr, 8); lBr += __shfl_xor(lBr, 8);                 \
        const float invA = 1.0f / lAr;                                        \
        const float invB = 1.0f / lBr;                                        \
        const int rowA = m0 + quad * 4 + R;                                   \
        float* opA = out + (b * SL + rowA) * DOUT + h * DH + l15;             \
        float* opB = opA + 16 * DOUT;                                         \
        opA[0] = oA0[R] * invA;  opA[16] = oA1[R] * invA;                     \
        opA[32] = oA2[R] * invA; opA[48] = oA3[R] * invA;                     \
        opB[0] = oB0[R] * invB;  opB[16] = oB1[R] * invB;                     \
        opB[32] = oB2[R] * invB; opB[48] = oB3[R] * invB;                     \
    }
        OUT_R(0, lA0, lB0)
        OUT_R(1, lA1, lB1)
        OUT_R(2, lA2, lB2)
        OUT_R(3, lA3, lB3)
#undef OUT_R
    }
}

extern "C" void kernel_launch(void* const* d_in, const int* in_sizes, int n_in,
                              void* d_out, int out_size, void* d_ws, size_t ws_size,
                              hipStream_t stream) {
    const float* Qs = (const float*)d_in[0];
    const float* Ks = (const float*)d_in[1];
    const float* Vs = (const float*)d_in[2];
    const float* WQ = (const float*)d_in[3];
    const float* WK = (const float*)d_in[4];
    const float* WV = (const float*)d_in[5];
    float* out = (float*)d_out;

    unsigned short* xb = (unsigned short*)d_ws;          // 3*8192*512 (tiled+swz)
    unsigned short* wt = xb + 3 * 8192 * DIN;            // 3*512*512 (tiled+swz)
    unsigned short* qw = wt + 3 * DIN * DOUT;            // frag-blocked, pre-scaled
    unsigned short* ks = qw + NB * NH * SL * DH;         // blocked
    unsigned short* vs = ks + NB * NH * SL * DH;         // blocked+permuted

    prep_kernel<<<dim3(6336), 256, 0, stream>>>(Qs, Ks, Vs, WQ, WK, WV, xb, wt);
    proj_kernel<<<dim3(256, 3), 256, 0, stream>>>(xb, wt, qw, ks, vs);
    attn_kernel<<<dim3(1024), 256, 0, stream>>>(qw, ks, vs, out);
}

// Round 10
// 153.030 us; speedup vs baseline: 1.1091x; 1.0217x over previous
//
#include <hip/hip_runtime.h>

#define NH 8
#define DH 64
#define SL 1024
#define NB 8
#define DIN 512
#define DOUT 512
#define PS 72  // P-tile LDS row stride in ushorts

typedef __bf16 bf16x8 __attribute__((ext_vector_type(8)));
typedef float floatx4 __attribute__((ext_vector_type(4)));
typedef unsigned short ushortx8 __attribute__((ext_vector_type(8)));

__device__ __forceinline__ unsigned short f2bf(float f) {
    unsigned int u = __builtin_bit_cast(unsigned int, f);
    u += 0x7FFFu + ((u >> 16) & 1u);
    return (unsigned short)(u >> 16);
}

__device__ __forceinline__ floatx4 mfma_bf16(bf16x8 a, bf16x8 b, floatx4 c) {
    return __builtin_amdgcn_mfma_f32_16x16x32_bf16(a, b, c, 0, 0, 0);
}

__device__ __forceinline__ void gld_lds16(const unsigned short* g, unsigned short* l) {
    __builtin_amdgcn_global_load_lds(
        (const __attribute__((address_space(1))) unsigned int*)g,
        (__attribute__((address_space(3))) unsigned int*)l, 16, 0, 0);
}

// bf16-truncate-pack two floats into one u32 (low short = bf(a), high = bf(b))
__device__ __forceinline__ unsigned int pack_bf2(float a, float b) {
    return __builtin_amdgcn_perm(__builtin_bit_cast(unsigned int, b),
                                 __builtin_bit_cast(unsigned int, a), 0x07060302u);
}

// Merged prep kernel:
//  blocks [0, 6144): X fp32 -> bf16 tiled+swizzled
//  blocks [6144, 6336): W -> transposed bf16 tiled+swizzled
// R18: X-conv blocks XCD-ALIGNED with proj's readers. proj XCD x reads mblks
// [8x,8x+8) (rows [1024x,1024x+1024) => t in [256x,256x+256)). Decode
// x=bid&7, t=x*256+(j&255) puts the WRITER of those xb lines on the same XCD
// as the reader; per-XCD xb share = 3.1 MB < 4 MB L2, so proj's first-touch
// A-reads become L2 hits instead of 900-cy HBM misses (FETCH was 18.5 MB).
__global__ __launch_bounds__(256) void prep_kernel(const float* __restrict__ Qs,
                                                   const float* __restrict__ Ks,
                                                   const float* __restrict__ Vs,
                                                   const float* __restrict__ WQ,
                                                   const float* __restrict__ WK,
                                                   const float* __restrict__ WV,
                                                   unsigned short* __restrict__ xb,
                                                   unsigned short* __restrict__ wt) {
    __shared__ unsigned short tile[64][68];
    const int bid = blockIdx.x;
    if (bid < 6144) {
        // ---- X conversion: xb[z][(row/128)*8 + k/64][row%128][((k%64/8)^(row&7))*8 + k%8]
        // XCD-aligned decode (R18): slot bid -> XCD bid&7 owns t in [256x, 256x+256).
        const int x = bid & 7;
        const int j = bid >> 3;               // 0..767
        const int z = j >> 8;                 // 0..2
        const int t = x * 256 + (j & 255);    // work index 0..2047 (rows t*4..t*4+4)
        const float* X = (z == 0) ? Qs : (z == 1 ? Ks : Vs);
        const int e = t * 256 + threadIdx.x;  // element-group index (8 floats each)
        const int row = e >> 6, c = e & 63;
        const float4 a = *(const float4*)(X + e * 8);
        const float4 b = *(const float4*)(X + e * 8 + 4);
        ushortx8 o;
        o[0] = f2bf(a.x); o[1] = f2bf(a.y); o[2] = f2bf(a.z); o[3] = f2bf(a.w);
        o[4] = f2bf(b.x); o[5] = f2bf(b.y); o[6] = f2bf(b.z); o[7] = f2bf(b.w);
        const int dst = (((row >> 7) * 8 + (c >> 3)) * 128 + (row & 127)) * 64 +
                        (((c & 7) ^ (row & 7)) * 8);
        *(ushortx8*)(xb + z * 8192 * DIN + dst) = o;
    } else {
        // ---- W transpose: wt[(z*4+n/128)*8 + k/64][n%128][swz chunk]
        const int b2 = bid - 6144;
        const int z = b2 >> 6;
        const int r = b2 & 63;
        const float* W = (z == 0) ? WQ : (z == 1 ? WK : WV);
        const int k0 = (r >> 3) * 64, n0 = (r & 7) * 64;
        const int tn = threadIdx.x & 63, tk = threadIdx.x >> 6;
#pragma unroll
        for (int i = 0; i < 16; ++i) {
            const int kk = tk + i * 4;
            tile[tn][kk] = f2bf(W[(k0 + kk) * DOUT + n0 + tn]);
        }
        __syncthreads();
#pragma unroll
        for (int i = 0; i < 16; ++i) {
            const int nn = tk + i * 4;
            const int n = n0 + nn, k = k0 + tn;
            const int dst = (((z * 4 + (n >> 7)) * 8 + (k >> 6)) * 128 + (n & 127)) * 64 +
                            ((((k >> 3) & 7) ^ (n & 7)) * 8) + (k & 7);
            wt[dst] = tile[nn][tn];
        }
    }
}

// m97-style GEMM, 128x128xBK64, global_load_lds staging, LDS-assembled epilogue.
// R14 T3 2-phase pipeline (best measured): stage(k+1) in flight during
// compute(k); one barrier per K-step. Epilogue image aliases buf0.
__global__ __launch_bounds__(256) void proj_kernel(const unsigned short* __restrict__ xbt,
                                                   const unsigned short* __restrict__ wtt,
                                                   unsigned short* __restrict__ qw,
                                                   unsigned short* __restrict__ ks,
                                                   unsigned short* __restrict__ vs) {
    __shared__ __align__(16) unsigned short S[32768];  // [buf][As 8192 | Bs 8192] x2
    const int z = blockIdx.y;
    const int wg = blockIdx.x;        // 0..255
    const int ix = wg >> 3;           // index within this XCD's chunk (round-robin model)
    const int mblk = (wg & 7) * 8 + (ix >> 2);
    const int nblk = ix & 3;
    const int w = threadIdx.x >> 6, lane = threadIdx.x & 63;
    const int l15 = lane & 15, quad = lane >> 4;
    const int wm = w >> 1, wn = w & 1;
    const int soff = lane * 8;  // identity: swizzle lives in the stored layout
    const unsigned short* Ab = xbt + z * (8192 * DIN) + mblk * 8 * 8192 + (w * 4) * 512 + soff;
    const unsigned short* Bb = wtt + (z * 4 + nblk) * 8 * 8192 + (w * 4) * 512 + soff;

    floatx4 acc[4][4];
#pragma unroll
    for (int i = 0; i < 4; ++i)
#pragma unroll
        for (int j = 0; j < 4; ++j) acc[i][j] = floatx4{0.f, 0.f, 0.f, 0.f};

    auto STAGE = [&](int buf, int kblk) {
        unsigned short* Asw = &S[buf * 16384 + (w * 4) * 512];
        unsigned short* Bsw = &S[buf * 16384 + 8192 + (w * 4) * 512];
#pragma unroll
        for (int i = 0; i < 4; ++i) {
            gld_lds16(Ab + kblk * 8192 + i * 512, Asw + i * 512);
            gld_lds16(Bb + kblk * 8192 + i * 512, Bsw + i * 512);
        }
    };

    auto COMPUTE = [&](int buf) {
        const unsigned short* Asb = &S[buf * 16384];
        const unsigned short* Bsb = &S[buf * 16384 + 8192];
#pragma unroll
        for (int ksub = 0; ksub < 2; ++ksub) {
            bf16x8 af[4], bfr[4];
#pragma unroll
            for (int mi = 0; mi < 4; ++mi) {
                const int row = wm * 64 + mi * 16 + l15;
                af[mi] = *(const bf16x8*)&Asb[row * 64 + (((quad + ksub * 4) ^ (l15 & 7)) * 8)];
            }
#pragma unroll
            for (int nt = 0; nt < 4; ++nt) {
                const int row = wn * 64 + nt * 16 + l15;
                bfr[nt] = *(const bf16x8*)&Bsb[row * 64 + (((quad + ksub * 4) ^ (l15 & 7)) * 8)];
            }
#pragma unroll
            for (int mi = 0; mi < 4; ++mi)
#pragma unroll
                for (int nt = 0; nt < 4; ++nt)
                    acc[mi][nt] = mfma_bf16(af[mi], bfr[nt], acc[mi][nt]);
        }
    };

    // T3 2-phase: prologue stage + drain, then overlap stage(k+1) with compute(k).
    STAGE(0, 0);
    __syncthreads();  // vmcnt(0) drain: buf0 ready
    for (int kblk = 0; kblk < 7; ++kblk) {
        STAGE((kblk + 1) & 1, kblk + 1);  // in flight during compute below
        COMPUTE(kblk & 1);
        __syncthreads();  // drains vmcnt(0): next buf ready; all waves done with cur
    }
    COMPUTE(1);

    // ---- epilogue: build output-byte-exact image in LDS (aliases buf0) ----
    __syncthreads();
#pragma unroll
    for (int mi = 0; mi < 4; ++mi)
#pragma unroll
        for (int nt = 0; nt < 4; ++nt)
#pragma unroll
            for (int r = 0; r < 4; ++r) {
                const int a = wm * 64 + mi * 16 + quad * 4 + r;   // tile row 0..127
                const int c = wn * 64 + nt * 16 + l15;            // tile col 0..127
                const int h = c >> 6, dh = c & 63;
                float v = acc[mi][nt][r];
                int lidx;
                if (z == 0) {
                    v *= 0.18033688f;  // 0.125 * log2(e): attn uses exp2
                    // q fragment-blocked image: [h][ltile 8][kc 8][l15 16][8]
                    lidx = h * 8192 + (a >> 4) * 1024 + (dh >> 3) * 128 + (a & 15) * 8 + (dh & 7);
                } else if (z == 1) {
                    lidx = (((((h << 3) + (a >> 4)) << 1) | (dh >> 5))) * 512 +
                           (a & 15) * 32 + (dh & 31);
                } else {
                    const int s64 = ((a & 15) << 2) | ((a >> 4) & 3);
                    lidx = ((((h << 1) | (a >> 6)) << 1) | (s64 >> 5)) * 2048 +
                           dh * 32 + (s64 & 31);
                }
                S[lidx] = f2bf(v);
            }
    __syncthreads();

    const int b = mblk >> 3;
    const int li0 = (mblk & 7) * 128;
    const int tid = threadIdx.x;
    unsigned short* outp = (z == 0) ? qw : (z == 1 ? ks : vs);
#pragma unroll
    for (int j = 0; j < 8; ++j) {
        const int off = j * 2048 + tid * 8;
        const ushortx8 val = *(const ushortx8*)(S + off);
        int gidx;
        if (z == 0) {
            const int h = off >> 13, o13 = off & 8191;
            gidx = ((b * 8 + nblk * 2 + h) * 64 + (li0 >> 4) + (o13 >> 10)) * 1024 + (o13 & 1023);
        } else if (z == 1) {
            const int region = off >> 9, pos = off & 511;
            const int h = region >> 4, g = (region >> 1) & 7, d5 = region & 1;
            gidx = (((b * 8 + nblk * 2 + h) * 64 + (li0 >> 4) + g) * 2 + d5) * 512 + pos;
        } else {
            const int region = off >> 11, pos = off & 2047;
            const int h = region >> 2, l6 = (region >> 1) & 1, s5 = region & 1;
            gidx = ((b * 8 + nblk * 2 + h) * 32 + (li0 >> 5) + l6 * 2 + s5) * 2048 + pos;
        }
        *(ushortx8*)(outp + gidx) = val;
    }
}

// One K-frame (64 keys) for a 32-row q-pair. ALL state in individually named
// locals / references. Compile-time DOMASK.
template <bool DOMASK>
__device__ __forceinline__ void frame_step(
    int kt, int m0, int l15, int quad,
    const unsigned short* __restrict__ ksb,
    const unsigned short* __restrict__ vsb,
    unsigned short* myPs,
    bf16x8 aQA0, bf16x8 aQA1, bf16x8 aQB0, bf16x8 aQB1,
    floatx4& oA0, floatx4& oA1, floatx4& oA2, floatx4& oA3,
    floatx4& oB0, floatx4& oB1, floatx4& oB2, floatx4& oB3,
    float& lA0, float& lA1, float& lA2, float& lA3,
    float& lB0, float& lB1, float& lB2, float& lB3) {
    const floatx4 zf = {0.f, 0.f, 0.f, 0.f};
    const unsigned short* kp = ksb + (kt >> 4) * 1024;
    floatx4 sA0 = zf, sA1 = zf, sA2 = zf, sA3 = zf;
    floatx4 sB0 = zf, sB1 = zf, sB2 = zf, sB3 = zf;
    __builtin_amdgcn_s_setprio(1);
#define QK_T(T, SA, SB)                                                     \
    if (!DOMASK || (kt + T * 16 <= m0 + 31)) {                              \
        const bf16x8 k0_ = *(const bf16x8*)(kp + T * 1024);                 \
        const bf16x8 k1_ = *(const bf16x8*)(kp + T * 1024 + 512);           \
        if (!DOMASK || (kt + T * 16 <= m0 + 15))                            \
            SA = mfma_bf16(aQA1, k1_, mfma_bf16(aQA0, k0_, zf));            \
        SB = mfma_bf16(aQB1, k1_, mfma_bf16(aQB0, k0_, zf));                \
    }
    QK_T(0, sA0, sB0)
    QK_T(1, sA1, sB1)
    QK_T(2, sA2, sB2)
    QK_T(3, sA3, sB3)
#undef QK_T
    __builtin_amdgcn_s_setprio(0);
    // V after K: vmcnt in-order, QK must not wait behind V; V hides under TAIL.
    const unsigned short* vb = vsb + (kt >> 5) * 2048;
    const bf16x8 v00 = *(const bf16x8*)(vb);
    const bf16x8 v01 = *(const bf16x8*)(vb + 512);
    const bf16x8 v02 = *(const bf16x8*)(vb + 1024);
    const bf16x8 v03 = *(const bf16x8*)(vb + 1536);
    const bf16x8 v10 = *(const bf16x8*)(vb + 2048);
    const bf16x8 v11 = *(const bf16x8*)(vb + 2560);
    const bf16x8 v12 = *(const bf16x8*)(vb + 3072);
    const bf16x8 v13 = *(const bf16x8*)(vb + 3584);
#define TAIL_R(R, LA, LB)                                                    \
    {                                                                        \
        const int rowA = m0 + quad * 4 + R;                                  \
        float pa0 = __builtin_amdgcn_exp2f(sA0[R]);                          \
        float pa1 = __builtin_amdgcn_exp2f(sA1[R]);                          \
        float pa2 = __builtin_amdgcn_exp2f(sA2[R]);                          \
        float pa3 = __builtin_amdgcn_exp2f(sA3[R]);                          \
        float pb0 = __builtin_amdgcn_exp2f(sB0[R]);                          \
        float pb1 = __builtin_amdgcn_exp2f(sB1[R]);                          \
        float pb2 = __builtin_amdgcn_exp2f(sB2[R]);                          \
        float pb3 = __builtin_amdgcn_exp2f(sB3[R]);                          \
        if (DOMASK) {                                                        \
            if (kt + l15 > rowA) pa0 = 0.f;                                  \
            if (kt + 16 + l15 > rowA) pa1 = 0.f;                             \
            if (kt + 32 + l15 > rowA) pa2 = 0.f;                             \
            if (kt + 48 + l15 > rowA) pa3 = 0.f;                             \
            if (kt + l15 > rowA + 16) pb0 = 0.f;                             \
            if (kt + 16 + l15 > rowA + 16) pb1 = 0.f;                        \
            if (kt + 32 + l15 > rowA + 16) pb2 = 0.f;                        \
            if (kt + 48 + l15 > rowA + 16) pb3 = 0.f;                        \
        }                                                                    \
        LA += (pa0 + pa1) + (pa2 + pa3);                                     \
        LB += (pb0 + pb1) + (pb2 + pb3);                                     \
        uint2 pkA, pkB;                                                      \
        pkA.x = pack_bf2(pa0, pa1);                                          \
        pkA.y = pack_bf2(pa2, pa3);                                          \
        pkB.x = pack_bf2(pb0, pb1);                                          \
        pkB.y = pack_bf2(pb2, pb3);                                          \
        *(uint2*)(myPs + (quad * 4 + R) * PS + l15 * 4) = pkA;               \
        *(uint2*)(myPs + (16 + quad * 4 + R) * PS + l15 * 4) = pkB;          \
    }
    TAIL_R(0, lA0, lB0)
    TAIL_R(1, lA1, lB1)
    TAIL_R(2, lA2, lB2)
    TAIL_R(3, lA3, lB3)
#undef TAIL_R
    __builtin_amdgcn_wave_barrier();
    const bf16x8 aPA0 = *(const bf16x8*)(myPs + l15 * PS + quad * 8);
    const bf16x8 aPA1 = *(const bf16x8*)(myPs + l15 * PS + 32 + quad * 8);
    const bf16x8 aPB0 = *(const bf16x8*)(myPs + (16 + l15) * PS + quad * 8);
    const bf16x8 aPB1 = *(const bf16x8*)(myPs + (16 + l15) * PS + 32 + quad * 8);
    __builtin_amdgcn_wave_barrier();
    __builtin_amdgcn_s_setprio(1);
    oA0 = mfma_bf16(aPA1, v10, mfma_bf16(aPA0, v00, oA0));
    oA1 = mfma_bf16(aPA1, v11, mfma_bf16(aPA0, v01, oA1));
    oA2 = mfma_bf16(aPA1, v12, mfma_bf16(aPA0, v02, oA2));
    oA3 = mfma_bf16(aPA1, v13, mfma_bf16(aPA0, v03, oA3));
    oB0 = mfma_bf16(aPB1, v10, mfma_bf16(aPB0, v00, oB0));
    oB1 = mfma_bf16(aPB1, v11, mfma_bf16(aPB0, v01, oB1));
    oB2 = mfma_bf16(aPB1, v12, mfma_bf16(aPB0, v02, oB2));
    oB3 = mfma_bf16(aPB1, v13, mfma_bf16(aPB0, v03, oB3));
    __builtin_amdgcn_s_setprio(0);
}

// Causal flash attention, split-K, M=32 per wave, named-register state.
__global__ __launch_bounds__(256) void attn_kernel(const unsigned short* __restrict__ qw,
                                                   const unsigned short* __restrict__ ksp,
                                                   const unsigned short* __restrict__ vsp,
                                                   float* __restrict__ out) {
    __shared__ union {
        unsigned short Ps[4][32 * PS];
        float Cb[2][64][42];
    } sh;
    const int w = threadIdx.x >> 6;
    const int lane = threadIdx.x & 63;
    const int l15 = lane & 15, quad = lane >> 4;
    // XCD-locality decode: dispatch slot s -> XCD s&7 (round-robin model).
    const int s_ = blockIdx.x;
    const int xcd = s_ & 7;
    const int idx = s_ >> 3;                 // 0..127
    const int bh = xcd * 8 + (idx & 7);      // XCD i serves heads 8i..8i+7
    const int xb16 = idx >> 3;               // 0..15
    const int b = bh >> 3, h = bh & 7;
    const int p = (w < 2) ? xb16 : 31 - xb16;  // tile-pair index 0..31
    const int half = w & 1;
    const int m0 = p * 32;                   // first q-row of the pair

    // Q fragments for both sub-tiles (2p = A, 2p+1 = B)
    const unsigned short* qpA = qw + (bh * 64 + 2 * p) * 1024 + quad * 128 + l15 * 8;
    const bf16x8 aQA0 = *(const bf16x8*)qpA;
    const bf16x8 aQA1 = *(const bf16x8*)(qpA + 512);
    const bf16x8 aQB0 = *(const bf16x8*)(qpA + 1024);
    const bf16x8 aQB1 = *(const bf16x8*)(qpA + 1536);

    const unsigned short* ksb = ksp + (bh * 64) * 2 * 512 + l15 * 32 + quad * 8;
    const unsigned short* vsb = vsp + (bh * 32 * 64 + l15) * 32 + quad * 8;
    unsigned short* myPs = sh.Ps[w];

    const floatx4 zf = {0.f, 0.f, 0.f, 0.f};
    floatx4 oA0 = zf, oA1 = zf, oA2 = zf, oA3 = zf;
    floatx4 oB0 = zf, oB1 = zf, oB2 = zf, oB3 = zf;
    float lA0 = 0.f, lA1 = 0.f, lA2 = 0.f, lA3 = 0.f;
    float lB0 = 0.f, lB1 = 0.f, lB2 = 0.f, lB3 = 0.f;

    // frames covering keys 0 .. m0+31 (B sub-tile's diagonal)
    const int nf = (m0 + 95) >> 6;
    const int last = nf - 1;
    for (int j = half; j < last; j += 2)
        frame_step<false>(j * 64, m0, l15, quad, ksb, vsb, myPs,
                          aQA0, aQA1, aQB0, aQB1,
                          oA0, oA1, oA2, oA3, oB0, oB1, oB2, oB3,
                          lA0, lA1, lA2, lA3, lB0, lB1, lB2, lB3);
    if ((last & 1) == half)
        frame_step<true>(last * 64, m0, l15, quad, ksb, vsb, myPs,
                         aQA0, aQA1, aQB0, aQB1,
                         oA0, oA1, oA2, oA3, oB0, oB1, oB2, oB3,
                         lA0, lA1, lA2, lA3, lB0, lB1, lB2, lB3);

    // combine split-K partners via LDS (pure addition; union with Ps -> barrier first)
    __syncthreads();
    if (half == 1) {
        float* cb = &sh.Cb[w >> 1][lane][0];
        cb[0] = oA0[0];  cb[1] = oA0[1];  cb[2] = oA0[2];  cb[3] = oA0[3];
        cb[4] = oA1[0];  cb[5] = oA1[1];  cb[6] = oA1[2];  cb[7] = oA1[3];
        cb[8] = oA2[0];  cb[9] = oA2[1];  cb[10] = oA2[2]; cb[11] = oA2[3];
        cb[12] = oA3[0]; cb[13] = oA3[1]; cb[14] = oA3[2]; cb[15] = oA3[3];
        cb[16] = oB0[0]; cb[17] = oB0[1]; cb[18] = oB0[2]; cb[19] = oB0[3];
        cb[20] = oB1[0]; cb[21] = oB1[1]; cb[22] = oB1[2]; cb[23] = oB1[3];
        cb[24] = oB2[0]; cb[25] = oB2[1]; cb[26] = oB2[2]; cb[27] = oB2[3];
        cb[28] = oB3[0]; cb[29] = oB3[1]; cb[30] = oB3[2]; cb[31] = oB3[3];
        cb[32] = lA0; cb[33] = lA1; cb[34] = lA2; cb[35] = lA3;
        cb[36] = lB0; cb[37] = lB1; cb[38] = lB2; cb[39] = lB3;
    }
    __syncthreads();
    if (half == 0) {
        const float* cb = &sh.Cb[w >> 1][lane][0];
        oA0[0] += cb[0];  oA0[1] += cb[1];  oA0[2] += cb[2];  oA0[3] += cb[3];
        oA1[0] += cb[4];  oA1[1] += cb[5];  oA1[2] += cb[6];  oA1[3] += cb[7];
        oA2[0] += cb[8];  oA2[1] += cb[9];  oA2[2] += cb[10]; oA2[3] += cb[11];
        oA3[0] += cb[12]; oA3[1] += cb[13]; oA3[2] += cb[14]; oA3[3] += cb[15];
        oB0[0] += cb[16]; oB0[1] += cb[17]; oB0[2] += cb[18]; oB0[3] += cb[19];
        oB1[0] += cb[20]; oB1[1] += cb[21]; oB1[2] += cb[22]; oB1[3] += cb[23];
        oB2[0] += cb[24]; oB2[1] += cb[25]; oB2[2] += cb[26]; oB2[3] += cb[27];
        oB3[0] += cb[28]; oB3[1] += cb[29]; oB3[2] += cb[30]; oB3[3] += cb[31];
        lA0 += cb[32]; lA1 += cb[33]; lA2 += cb[34]; lA3 += cb[35];
        lB0 += cb[36]; lB1 += cb[37]; lB2 += cb[38]; lB3 += cb[39];
#define OUT_R(R, LA, LB)                                                      \
    {                                                                         \
        float lAr = LA, lBr = LB;                                             \
        lAr += __shfl_xor(lAr, 1); lBr += __shfl_xor(lBr, 1);                 \
        lAr += __shfl_xor(lAr, 2); lBr += __shfl_xor(lBr, 2);                 \
        lAr += __shfl_xor(lAr, 4); lBr += __shfl_xor(lBr, 4);                 \
        lAr += __shfl_xor(lAr, 8); lBr += __shfl_xor(lBr, 8);                 \
        const float invA = 1.0f / lAr;                                        \
        const float invB = 1.0f / lBr;                                        \
        const int rowA = m0 + quad * 4 + R;                                   \
        float* opA = out + (b * SL + rowA) * DOUT + h * DH + l15;             \
        float* opB = opA + 16 * DOUT;                                         \
        opA[0] = oA0[R] * invA;  opA[16] = oA1[R] * invA;                     \
        opA[32] = oA2[R] * invA; opA[48] = oA3[R] * invA;                     \
        opB[0] = oB0[R] * invB;  opB[16] = oB1[R] * invB;                     \
        opB[32] = oB2[R] * invB; opB[48] = oB3[R] * invB;                     \
    }
        OUT_R(0, lA0, lB0)
        OUT_R(1, lA1, lB1)
        OUT_R(2, lA2, lB2)
        OUT_R(3, lA3, lB3)
#undef OUT_R
    }
}

extern "C" void kernel_launch(void* const* d_in, const int* in_sizes, int n_in,
                              void* d_out, int out_size, void* d_ws, size_t ws_size,
                              hipStream_t stream) {
    const float* Qs = (const float*)d_in[0];
    const float* Ks = (const float*)d_in[1];
    const float* Vs = (const float*)d_in[2];
    const float* WQ = (const float*)d_in[3];
    const float* WK = (const float*)d_in[4];
    const float* WV = (const float*)d_in[5];
    float* out = (float*)d_out;

    unsigned short* xb = (unsigned short*)d_ws;          // 3*8192*512 (tiled+swz)
    unsigned short* wt = xb + 3 * 8192 * DIN;            // 3*512*512 (tiled+swz)
    unsigned short* qw = wt + 3 * DIN * DOUT;            // frag-blocked, pre-scaled
    unsigned short* ks = qw + NB * NH * SL * DH;         // blocked
    unsigned short* vs = ks + NB * NH * SL * DH;         // blocked+permuted

    prep_kernel<<<dim3(6336), 256, 0, stream>>>(Qs, Ks, Vs, WQ, WK, WV, xb, wt);
    proj_kernel<<<dim3(256, 3), 256, 0, stream>>>(xb, wt, qw, ks, vs);
    attn_kernel<<<dim3(1024), 256, 0, stream>>>(qw, ks, vs, out);
}